// Round 6
// baseline (137.059 us; speedup 1.0000x reference)
//
#include <hip/hip_runtime.h>
#include <hip/hip_fp16.h>
#include <stdint.h>

#define JB 24
#define NP 131072      // 2^17
#define CH 16
#define G  128

// workspace sizes in half2 units (1 half2 = 4 B)
#define PLANE_H2 (JB*G*G*CH)   // 6,291,456 half2 per plane array (25.2 MB)
#define LINE_H2  (JB*G*CH)     // 49,152 half2 per line array

typedef _Float16 h2_t __attribute__((ext_vector_type(2)));

__device__ __forceinline__ float fdot2(uint32_t a, h2_t w, float c) {
#if __has_builtin(__builtin_amdgcn_fdot2)
    return __builtin_amdgcn_fdot2(__builtin_bit_cast(h2_t, a), w, c, false);
#else
    __half2 ha = __builtin_bit_cast(__half2, a);
    float2 fa = __half22float2(ha);
    h2_t wv = w;
    return c + fa.x * (float)wv[0] + fa.y * (float)wv[1];
#endif
}

// ---- pack planes: (J,C,H,W) fp32 -> (plane,J,y,x,c) half2 pairs (v[x], v[x+1]) ----
__global__ __launch_bounds__(256)
void pack_planes_kernel(const float* __restrict__ p0,
                        const float* __restrict__ p1,
                        const float* __restrict__ p2,
                        __half2* __restrict__ wsp) {
    __shared__ float lds[CH * (G + 1)];
    int b = blockIdx.x;
    int y = b & (G - 1);
    int j = (b >> 7) % JB;
    int p = b / (G * JB);
    const float* src = (p == 0 ? p0 : (p == 1 ? p1 : p2))
                       + ((size_t)j * CH) * (G * G) + (size_t)y * G;
    __half2* dst = wsp + ((size_t)(p * JB + j) * G + y) * (G * CH);
    int tid = threadIdx.x;
    for (int idx = tid; idx < G * CH; idx += 256) {
        int c = idx >> 7;
        int x = idx & (G - 1);
        lds[c * (G + 1) + x] = src[(size_t)c * G * G + x];
    }
    __syncthreads();
    for (int idx = tid; idx < G * CH; idx += 256) {
        int x = idx >> 4;
        int c = idx & 15;
        int x1 = (x < G - 1) ? x + 1 : x;
        float a = lds[c * (G + 1) + x];
        float bvv = lds[c * (G + 1) + x1];
        dst[idx] = __floats2half2_rn(a, bvv);
    }
}

// ---- pack lines: (J,C,L) fp32 -> (plane,J,z,c) half2 pairs (l[z], l[z+1]) ----
__global__ __launch_bounds__(256)
void pack_lines_kernel(const float* __restrict__ l0,
                       const float* __restrict__ l1,
                       const float* __restrict__ l2,
                       __half2* __restrict__ wsl) {
    int gid = blockIdx.x * 256 + threadIdx.x;
    if (gid >= 3 * LINE_H2) return;
    int p = gid / LINE_H2;
    int r = gid - p * LINE_H2;
    int j = r >> 11;
    int z = (r >> 4) & (G - 1);
    int c = r & 15;
    int z1 = (z < G - 1) ? z + 1 : z;
    const float* src = (p == 0 ? l0 : (p == 1 ? l1 : l2));
    float a = src[((size_t)j * CH + c) * G + z];
    float bvv = src[((size_t)j * CH + c) * G + z1];
    wsl[gid] = __floats2half2_rn(a, bvv);
}

// ---- main gather: 4 lanes/point, 2 points/lane, 18 loads in flight ----
__global__ __launch_bounds__(256, 4)
void tensorf_pair2_kernel(const float* __restrict__ xyz,
                          const uint32_t* __restrict__ wp,   // half2 units
                          const uint32_t* __restrict__ wl,   // half2 units
                          float* __restrict__ out) {
    const int NWG = (JB * NP * 2) / 256;   // 24576 blocks
    int bid = blockIdx.x;
    int wg = (bid & 7) * (NWG >> 3) + (bid >> 3);
    int gid = wg * 256 + threadIdx.x;
    int pair = gid >> 2;
    int l4 = gid & 3;
    int pt0 = pair * 2;
    if (pt0 >= JB * NP) return;
    int j = pt0 >> 17;                    // pt1 = pt0+1 is in the same j

    const int M0[3] = {0, 0, 1};
    const int M1[3] = {1, 2, 2};
    const int VZ[3] = {2, 1, 0};

    float co[2][3];
    #pragma unroll
    for (int p2 = 0; p2 < 2; ++p2) {
        size_t base = (size_t)(pt0 + p2) * 3;
        co[p2][0] = xyz[base + 0];
        co[p2][1] = xyz[base + 1];
        co[p2][2] = xyz[base + 2];
    }

    uint4 A[2][3], B[2][3], C[2][3];
    h2_t wxh[2][3], wzh[2][3];
    float wyv[2][3];

    // phase 1: compute all addresses, issue all 18 loads
    #pragma unroll
    for (int p2 = 0; p2 < 2; ++p2) {
        #pragma unroll
        for (int i = 0; i < 3; ++i) {
            float fx = (co[p2][M0[i]] + 1.f) * 63.5f;
            float fy = (co[p2][M1[i]] + 1.f) * 63.5f;
            float fz = (co[p2][VZ[i]] + 1.f) * 63.5f;
            float f0x = fminf(fmaxf(floorf(fx), 0.f), 126.f);
            float f0y = fminf(fmaxf(floorf(fy), 0.f), 126.f);
            float f0z = fminf(fmaxf(floorf(fz), 0.f), 126.f);
            int x0 = (int)f0x, y0 = (int)f0y, z0 = (int)f0z;
            float wx = fx - f0x, wz = fz - f0z;
            wyv[p2][i] = fy - f0y;
            wxh[p2][i] = h2_t{(_Float16)(1.f - wx), (_Float16)wx};
            wzh[p2][i] = h2_t{(_Float16)(1.f - wz), (_Float16)wz};

            int pb = ((i * JB + j) << 18) + (((y0 << 7) + x0) << 4) + (l4 << 2);
            A[p2][i] = *(const uint4*)(wp + pb);              // row y0
            B[p2][i] = *(const uint4*)(wp + pb + (G << 4));   // row y0+1
            int lb = ((i * JB + j) << 11) + (z0 << 4) + (l4 << 2);
            C[p2][i] = *(const uint4*)(wl + lb);              // line pair
        }
    }

    // phase 2: consume
    float s[2];
    #pragma unroll
    for (int p2 = 0; p2 < 2; ++p2) {
        float4 acc = {0.f, 0.f, 0.f, 0.f};
        #pragma unroll
        for (int i = 0; i < 3; ++i) {
            float wy = wyv[p2][i];
            h2_t wx = wxh[p2][i], wz = wzh[p2][i];
            float t0 = fdot2(A[p2][i].x, wx, 0.f);
            float t1 = fdot2(A[p2][i].y, wx, 0.f);
            float t2 = fdot2(A[p2][i].z, wx, 0.f);
            float t3 = fdot2(A[p2][i].w, wx, 0.f);
            float b0 = fdot2(B[p2][i].x, wx, 0.f);
            float b1 = fdot2(B[p2][i].y, wx, 0.f);
            float b2 = fdot2(B[p2][i].z, wx, 0.f);
            float b3 = fdot2(B[p2][i].w, wx, 0.f);
            float v0 = fdot2(C[p2][i].x, wz, 0.f);
            float v1 = fdot2(C[p2][i].y, wz, 0.f);
            float v2 = fdot2(C[p2][i].z, wz, 0.f);
            float v3 = fdot2(C[p2][i].w, wz, 0.f);
            float q0 = t0 + (b0 - t0) * wy;
            float q1 = t1 + (b1 - t1) * wy;
            float q2 = t2 + (b2 - t2) * wy;
            float q3 = t3 + (b3 - t3) * wy;
            acc.x = fmaf(q0, v0, acc.x);
            acc.y = fmaf(q1, v1, acc.y);
            acc.z = fmaf(q2, v2, acc.z);
            acc.w = fmaf(q3, v3, acc.w);
        }
        s[p2] = (acc.x + acc.y) + (acc.z + acc.w);
    }

    float s0 = s[0] + __shfl_xor(s[0], 1);
    s0 += __shfl_xor(s0, 2);
    float s1 = s[1] + __shfl_xor(s[1], 1);
    s1 += __shfl_xor(s1, 2);
    if (l4 == 0) {
        out[pt0]     = fmaxf(s0, 0.f);
        out[pt0 + 1] = fmaxf(s1, 0.f);
    }
}

// ---------------- fallback: direct layout fp32 (if ws too small) ----------------
__global__ __launch_bounds__(256)
void tensorf_direct_kernel(const float* __restrict__ xyz,
                           const float* __restrict__ p0,
                           const float* __restrict__ p1,
                           const float* __restrict__ p2,
                           const float* __restrict__ l0,
                           const float* __restrict__ l1,
                           const float* __restrict__ l2,
                           float* __restrict__ out) {
    int gid = blockIdx.x * 256 + threadIdx.x;
    if (gid >= JB * NP) return;
    int j = gid >> 17;
    float cx = xyz[(size_t)gid * 3 + 0];
    float cy = xyz[(size_t)gid * 3 + 1];
    float cz = xyz[(size_t)gid * 3 + 2];
    const float co[3] = {cx, cy, cz};
    const int M0[3] = {0, 0, 1};
    const int M1[3] = {1, 2, 2};
    const int VZ[3] = {2, 1, 0};
    const float* PP[3] = {p0, p1, p2};
    const float* LL[3] = {l0, l1, l2};

    float acc = 0.f;
    #pragma unroll
    for (int i = 0; i < 3; ++i) {
        float fx = (co[M0[i]] + 1.f) * 63.5f;
        float fy = (co[M1[i]] + 1.f) * 63.5f;
        float fz = (co[VZ[i]] + 1.f) * 63.5f;
        float f0x = fminf(fmaxf(floorf(fx), 0.f), 127.f);
        float f0y = fminf(fmaxf(floorf(fy), 0.f), 127.f);
        float f0z = fminf(fmaxf(floorf(fz), 0.f), 127.f);
        int x0 = (int)f0x, y0 = (int)f0y, z0 = (int)f0z;
        int x1 = min(x0 + 1, G - 1);
        int y1 = min(y0 + 1, G - 1);
        int z1 = min(z0 + 1, G - 1);
        float wx = fx - f0x, wy = fy - f0y, wz = fz - f0z;

        const float* p = PP[i] + (size_t)j * CH * G * G;
        const float* l = LL[i] + (size_t)j * CH * G;
        for (int c = 0; c < CH; ++c) {
            const float* pc = p + (size_t)c * G * G;
            float v00 = pc[(size_t)y0 * G + x0];
            float v01 = pc[(size_t)y0 * G + x1];
            float v10 = pc[(size_t)y1 * G + x0];
            float v11 = pc[(size_t)y1 * G + x1];
            float lc0 = l[(size_t)c * G + z0];
            float lc1 = l[(size_t)c * G + z1];
            float top = v00 + (v01 - v00) * wx;
            float bot = v10 + (v11 - v10) * wx;
            float pv  = top + (bot - top) * wy;
            float lv  = lc0 + (lc1 - lc0) * wz;
            acc += pv * lv;
        }
    }
    out[gid] = fmaxf(acc, 0.f);
}

extern "C" void kernel_launch(void* const* d_in, const int* in_sizes, int n_in,
                              void* d_out, int out_size, void* d_ws, size_t ws_size,
                              hipStream_t stream) {
    const float* xyz = (const float*)d_in[0];
    const float* p0  = (const float*)d_in[1];
    const float* l0  = (const float*)d_in[2];
    const float* p1  = (const float*)d_in[3];
    const float* l1  = (const float*)d_in[4];
    const float* p2  = (const float*)d_in[5];
    const float* l2  = (const float*)d_in[6];
    float* out = (float*)d_out;

    const size_t need = ((size_t)3 * PLANE_H2 + (size_t)3 * LINE_H2) * sizeof(__half2);
    const int npts = JB * NP;

    if (ws_size >= need) {
        __half2* wsp = (__half2*)d_ws;
        __half2* wsl = wsp + (size_t)3 * PLANE_H2;
        pack_planes_kernel<<<3 * JB * G, 256, 0, stream>>>(p0, p1, p2, wsp);
        pack_lines_kernel<<<(3 * LINE_H2 + 255) / 256, 256, 0, stream>>>(l0, l1, l2, wsl);
        const int nthreads = npts * 2;   // 6,291,456 -> 24576 blocks (divisible by 8)
        tensorf_pair2_kernel<<<nthreads / 256, 256, 0, stream>>>(
            xyz, (const uint32_t*)wsp, (const uint32_t*)wsl, out);
    } else {
        tensorf_direct_kernel<<<(npts + 255) / 256, 256, 0, stream>>>(xyz, p0, p1, p2, l0, l1, l2, out);
    }
}